// Round 4
// baseline (5064.829 us; speedup 1.0000x reference)
//
#include <hip/hip_runtime.h>
#include <hip/hip_bf16.h>

// Problem: B=64, S=512, I=256, H=512 LSTM forward.
// R4: persistent kernel, 64 WGs, ZERO barriers / flags / fences in the step
// loop. h is published as self-certifying u64 atoms: (epoch<<32)|2xbf16,
// via relaxed agent-scope (sc1, LLC-coherent) stores. Consumers poll the
// exact atoms they need per 32-hidden k-chunk, software-pipelined 2 deep,
// and feed MFMA as chunks arrive. Ring-2 h buffer is safe w/o barriers:
// writer of h(t+1) implies all WGs published h(t), which implies all WGs
// finished reading h(t-1) (the slot being overwritten).

#define BB 64
#define SS 512
#define II 256
#define HH 512
#define G4 2048
#define NWG 64
#define HJ 8    // hidden units per WG
#define NC 32   // gate columns per WG = 4*HJ

typedef __attribute__((ext_vector_type(8))) short bf16x8;
typedef __attribute__((ext_vector_type(4))) float f32x4;
typedef unsigned long long u64t;

// x [b][t][i] fp32 -> xb [t][b][i] bf16 (per-step A-operand layout)
__global__ void convert_x_kernel(const float* __restrict__ x,
                                 __hip_bfloat16* __restrict__ xb) {
  int blk = blockIdx.x;          // b*SS + t
  int b = blk >> 9;
  int t = blk & (SS - 1);
  int i = threadIdx.x;           // 0..255
  float v = x[(size_t)blk * II + i];
  xb[((size_t)t * BB + b) * II + i] = __float2bfloat16(v);
}

__device__ __forceinline__ u64t ld_llc_u64(const u64t* p) {
  return __hip_atomic_load((u64t*)p, __ATOMIC_RELAXED,
                           __HIP_MEMORY_SCOPE_AGENT);
}
__device__ __forceinline__ void st_llc_u64(u64t* p, u64t v) {
  __hip_atomic_store(p, v, __ATOMIC_RELAXED, __HIP_MEMORY_SCOPE_AGENT);
}

__global__ __launch_bounds__(256, 1)
void lstm_persistent(const float* __restrict__ W,
                     const float* __restrict__ U,
                     const float* __restrict__ bias,
                     const __hip_bfloat16* __restrict__ xb,
                     u64t* __restrict__ hpub,   // [2][BB][HH/2] epoch|2xbf16
                     float* __restrict__ out) {
  __shared__ alignas(16) __hip_bfloat16 Ut[NC][HH + 8];
  __shared__ alignas(16) __hip_bfloat16 Wt[NC][II + 8];
  __shared__ float gate[2][BB][NC + 1];   // double-buffered: 1 sync/step
  __shared__ float bia[NC];

  const int tid = threadIdx.x;
  const int wg = blockIdx.x;
  const int j0 = wg * HJ;

  // ---- one-time: stage U/W column slices (transposed, bf16) ----
  for (int idx = tid; idx < NC * HH; idx += 256) {
    int c = idx & (NC - 1);
    int k = idx >> 5;
    int g = c >> 3, j = c & 7;
    Ut[c][k] = __float2bfloat16(U[(size_t)k * G4 + g * HH + j0 + j]);
  }
  for (int idx = tid; idx < NC * II; idx += 256) {
    int c = idx & (NC - 1);
    int k = idx >> 5;
    int g = c >> 3, j = c & 7;
    Wt[c][k] = __float2bfloat16(W[(size_t)k * G4 + g * HH + j0 + j]);
  }
  if (tid < NC) {
    int g = tid >> 3, j = tid & 7;
    bia[tid] = bias[g * HH + j0 + j];
  }
  __syncthreads();

  const int wave = tid >> 6;
  const int lane = tid & 63;
  const int l16 = lane & 15;
  const int quad = lane >> 4;
  const int arow = wave * 16 + l16;   // batch row for A-fragment

  // per-thread cell state: pairs (pb, pj) and (pb, pj+1)
  float c0 = 0.f, c1 = 0.f;
  const int pb = (2 * tid) >> 3;      // batch
  const int pj = (2 * tid) & 7;       // even unit index within WG slice

  for (int t = 0; t < SS; ++t) {
    const __hip_bfloat16* xt = xb + (size_t)t * (BB * II);
    // h(t-1) lives in slot (t-1)&1 = (t&1)^1; h(t) goes to slot t&1
    const u64t* hr = hpub + (size_t)((t & 1) ^ 1) * (BB * (HH / 2))
                          + (size_t)arow * (HH / 2);
    u64t* hw = hpub + (size_t)(t & 1) * (BB * (HH / 2));
    const unsigned ewant = (unsigned)t;        // tag of h(t-1)
    const unsigned epub = (unsigned)(t + 1);   // tag we publish for h(t)

    float b0 = bia[l16], b1 = bia[16 + l16];
    f32x4 acc0 = {b0, b0, b0, b0};  // cols 0..15  (gates i,f)
    f32x4 acc1 = {b1, b1, b1, b1};  // cols 16..31 (gates g,o)

    // prefetch h chunk 0 (4 u64 = this lane's 8 hidden of batch arow)
    u64t qa[4], qb[4];
#pragma unroll
    for (int i = 0; i < 4; ++i) qa[i] = ld_llc_u64(hr + quad * 4 + i);

    // ---- x @ W : overlaps the h(t-1) flight ----
#pragma unroll
    for (int ks = 0; ks < II / 32; ++ks) {
      bf16x8 a = *(const bf16x8*)(xt + (size_t)arow * II + ks * 32 + quad * 8);
      bf16x8 fb0 = *(const bf16x8*)(&Wt[l16][ks * 32 + quad * 8]);
      bf16x8 fb1 = *(const bf16x8*)(&Wt[16 + l16][ks * 32 + quad * 8]);
      acc0 = __builtin_amdgcn_mfma_f32_16x16x32_bf16(a, fb0, acc0, 0, 0, 0);
      acc1 = __builtin_amdgcn_mfma_f32_16x16x32_bf16(a, fb1, acc1, 0, 0, 0);
    }

    // ---- h @ U : per-chunk self-certified consume, pipelined 2 deep ----
#pragma unroll
    for (int ks = 0; ks < HH / 32; ++ks) {
      u64t* qc = (ks & 1) ? qb : qa;
      u64t* qn = (ks & 1) ? qa : qb;
      if (ks < HH / 32 - 1) {
#pragma unroll
        for (int i = 0; i < 4; ++i)
          qn[i] = ld_llc_u64(hr + (ks + 1) * 16 + quad * 4 + i);
      }
      bool ok = ((unsigned)(qc[0] >> 32) == ewant) &
                ((unsigned)(qc[1] >> 32) == ewant) &
                ((unsigned)(qc[2] >> 32) == ewant) &
                ((unsigned)(qc[3] >> 32) == ewant);
      while (!__all(ok)) {   // straggler path: serial re-poll of this chunk
#pragma unroll
        for (int i = 0; i < 4; ++i)
          qc[i] = ld_llc_u64(hr + ks * 16 + quad * 4 + i);
        ok = ((unsigned)(qc[0] >> 32) == ewant) &
             ((unsigned)(qc[1] >> 32) == ewant) &
             ((unsigned)(qc[2] >> 32) == ewant) &
             ((unsigned)(qc[3] >> 32) == ewant);
      }
      union { unsigned w[4]; bf16x8 v; } af;
#pragma unroll
      for (int i = 0; i < 4; ++i) af.w[i] = (unsigned)qc[i];
      bf16x8 fb0 = *(const bf16x8*)(&Ut[l16][ks * 32 + quad * 8]);
      bf16x8 fb1 = *(const bf16x8*)(&Ut[16 + l16][ks * 32 + quad * 8]);
      acc0 = __builtin_amdgcn_mfma_f32_16x16x32_bf16(af.v, fb0, acc0, 0, 0, 0);
      acc1 = __builtin_amdgcn_mfma_f32_16x16x32_bf16(af.v, fb1, acc1, 0, 0, 0);
    }

    // D layout (verified m89): row = quad*4 + reg, col = lane&15
#pragma unroll
    for (int r = 0; r < 4; ++r) {
      int row = wave * 16 + quad * 4 + r;
      gate[t & 1][row][l16] = acc0[r];
      gate[t & 1][row][16 + l16] = acc1[r];
    }
    __syncthreads();   // the ONLY sync in the step (gate dbuf handles WAR)

    // ---- elementwise cell update: 2 units, same batch, one u64 publish ----
    float hv[2];
#pragma unroll
    for (int s = 0; s < 2; ++s) {
      int j = pj + s;
      float& cst = s ? c1 : c0;
      float xi = gate[t & 1][pb][j];
      float xf = gate[t & 1][pb][8 + j];
      float xg = gate[t & 1][pb][16 + j];
      float xo = gate[t & 1][pb][24 + j];
      float it = 1.f / (1.f + __expf(-xi));
      float ft = 1.f / (1.f + __expf(-xf));
      float gx = fminf(fmaxf(xg, -15.f), 15.f);
      float eg = __expf(2.f * gx);
      float gt = (eg - 1.f) / (eg + 1.f);
      float ot = 1.f / (1.f + __expf(-xo));
      cst = ft * cst + it * gt;
      float cc = fminf(fmaxf(cst, -15.f), 15.f);
      float ec = __expf(2.f * cc);
      float th = (ec - 1.f) / (ec + 1.f);
      hv[s] = ot * th;
    }
    // publish FIRST (critical path), then the out stores
    union { __hip_bfloat16 b[2]; unsigned u; } hp;
    hp.b[0] = __float2bfloat16(hv[0]);
    hp.b[1] = __float2bfloat16(hv[1]);
    u64t atom = ((u64t)epub << 32) | (u64t)hp.u;
    st_llc_u64(hw + (size_t)pb * (HH / 2) + (j0 + pj) / 2, atom);

    *(float2*)(out + (size_t)pb * (SS * HH) + (size_t)t * HH + j0 + pj) =
        make_float2(hv[0], hv[1]);
    if (t == SS - 1) {
      size_t base = (size_t)BB * SS * HH;
      *(float2*)(out + base + (size_t)pb * HH + j0 + pj) =
          make_float2(hv[0], hv[1]);                       // h_f
      *(float2*)(out + base + (size_t)BB * HH + (size_t)pb * HH + j0 + pj) =
          make_float2(c0, c1);                             // c_f
    }
  }
}

extern "C" void kernel_launch(void* const* d_in, const int* in_sizes, int n_in,
                              void* d_out, int out_size, void* d_ws, size_t ws_size,
                              hipStream_t stream) {
  const float* x = (const float*)d_in[0];     // [64,512,256]
  const float* W = (const float*)d_in[1];     // [256,2048]
  const float* U = (const float*)d_in[2];     // [512,2048]
  const float* bias = (const float*)d_in[3];  // [2048]
  float* out = (float*)d_out;

  char* ws = (char*)d_ws;
  u64t* hpub = (u64t*)ws;                                  // 2*64*256*8 = 256KB
  __hip_bfloat16* xb = (__hip_bfloat16*)(ws + 2 * BB * (HH / 2) * sizeof(u64t));
  // zero hpub: tag 0 == epoch of h(-1), value 0 == h(-1). Self-consistent.
  hipMemsetAsync(d_ws, 0, 2 * BB * (HH / 2) * sizeof(u64t), stream);

  convert_x_kernel<<<BB * SS, II, 0, stream>>>(x, xb);
  lstm_persistent<<<NWG, 256, 0, stream>>>(W, U, bias, xb, hpub, out);
}

// Round 5
// 2176.522 us; speedup vs baseline: 2.3270x; 2.3270x over previous
//
#include <hip/hip_runtime.h>
#include <hip/hip_bf16.h>

// B=64, S=512, I=256, H=512 LSTM forward.
// R5: batch-group decomposition. The recurrence is independent across batch,
// so split into 4 groups x 16 batches; only the 16 WGs of a group sync.
// Each WG owns 128 gate cols (32 hidden units) with its U-slice in LDS.
// h published as self-certifying u64 atoms (tag<<32 | 2xbf16) via relaxed
// agent-scope stores; consumers bulk-issue 16 coalesced atomic loads/thread
// (their group's full 16x512 h = 32 KB) and do ONE combined tag check.
// No flags, no fences, no cache maintenance, no global barrier: the spin IS
// the group barrier. Ring-2 slots safe: any WG's step-t+1 publish requires
// all group WGs' tag t+1, which (two __syncthreads later than their slot
// consumption) implies every thread consumed the slot being overwritten.

#define BB 64
#define SS 512
#define II 256
#define HH 512
#define G4 2048
#define NGRP 4     // batch groups
#define GB 16      // batches per group
#define NWPG 16    // WGs per group
#define NCOL 128   // gate cols per WG = 4 gates x 32 units
#define NU 32      // hidden units per WG

typedef __attribute__((ext_vector_type(8))) short bf16x8;
typedef __attribute__((ext_vector_type(4))) float f32x4;
typedef unsigned long long u64t;

__device__ __forceinline__ u64t ld_llc_u64(const u64t* p) {
  return __hip_atomic_load((u64t*)p, __ATOMIC_RELAXED,
                           __HIP_MEMORY_SCOPE_AGENT);
}
__device__ __forceinline__ void st_llc_u64(u64t* p, u64t v) {
  __hip_atomic_store(p, v, __ATOMIC_RELAXED, __HIP_MEMORY_SCOPE_AGENT);
}

// x [b][t][i] fp32 -> xb [t][b][i] bf16
__global__ void convert_x_kernel(const float* __restrict__ x,
                                 __hip_bfloat16* __restrict__ xb) {
  int blk = blockIdx.x;          // b*SS + t
  int b = blk >> 9;
  int t = blk & (SS - 1);
  int i = threadIdx.x;
  xb[((size_t)t * BB + b) * II + i] = __float2bfloat16(x[(size_t)blk * II + i]);
}

// W [256][2048] fp32 -> Wt [2048][256] bf16 (row = gate col, for B-frags)
__global__ void transpose_w_kernel(const float* __restrict__ W,
                                   __hip_bfloat16* __restrict__ Wt) {
  __shared__ __hip_bfloat16 tile[64][64 + 8];
  int kb = blockIdx.x & 3;       // 4 k-blocks
  int nb = blockIdx.x >> 2;      // 32 n-blocks
  int k0 = kb * 64, nb0 = nb * 64;
#pragma unroll
  for (int p = 0; p < 16; ++p) {
    int r = p * 4 + (threadIdx.x >> 6);
    int c = threadIdx.x & 63;
    tile[r][c] = __float2bfloat16(W[(size_t)(k0 + r) * G4 + nb0 + c]);
  }
  __syncthreads();
#pragma unroll
  for (int p = 0; p < 16; ++p) {
    int n = p * 4 + (threadIdx.x >> 6);
    int k = threadIdx.x & 63;
    Wt[(size_t)(nb0 + n) * II + k0 + k] = tile[k][n];
  }
}

__global__ __launch_bounds__(256, 1)
void lstm_step(const float* __restrict__ U,
               const float* __restrict__ bias,
               const __hip_bfloat16* __restrict__ xb,
               const __hip_bfloat16* __restrict__ Wt,
               u64t* __restrict__ hpub,   // [NGRP][2][GB*256] u64
               float* __restrict__ out) {
  // LDS: Ut 133.1K + hL 16.6K + gate 8.4K + bias 0.5K = 158.7K (<160K)
  __shared__ alignas(16) __hip_bfloat16 Ut[NCOL][HH + 8];
  __shared__ alignas(16) __hip_bfloat16 hL[GB][HH + 8];
  __shared__ float gate[GB][NCOL + 4];
  __shared__ float bia[NCOL];

  const int tid = threadIdx.x;
  const int wgid = blockIdx.x;
  const int grp = wgid >> 4;     // batch group 0..3
  const int w16 = wgid & 15;     // WG within group
  const int n0 = w16 * NU;       // hidden-unit offset of this WG's slice

  // ---- one-time: stage U column-slice (transposed, bf16) + bias ----
  // local col c = g*32 + j  <->  global col g*512 + n0 + j
  for (int i = tid; i < NCOL * HH; i += 256) {
    int c = i & (NCOL - 1);
    int k = i >> 7;
    int g = c >> 5, j = c & 31;
    Ut[c][k] = __float2bfloat16(U[(size_t)k * G4 + g * HH + n0 + j]);
  }
  if (tid < NCOL) {
    int g = tid >> 5, j = tid & 31;
    bia[tid] = bias[g * HH + n0 + j];
  }
  __syncthreads();

  const int lane = tid & 63;
  const int wave = tid >> 6;
  const int l16 = lane & 15;
  const int quad = lane >> 4;
  const int c0i = (2 * wave) * 16 + l16;       // this lane's col, n-tile 0
  const int c1i = (2 * wave + 1) * 16 + l16;   // this lane's col, n-tile 1

  // B-frag row pointers in Wt (global col = (c>>5)*512 + n0 + (c&31))
  const __hip_bfloat16* wrow0 =
      Wt + (size_t)((c0i >> 5) * HH + n0 + (c0i & 31)) * II;
  const __hip_bfloat16* wrow1 =
      Wt + (size_t)((c1i >> 5) * HH + n0 + (c1i & 31)) * II;

  // eltwise ownership: thread -> cells (eb, ej) and (eb, ej+1)
  const int eb = (2 * tid) >> 5;   // batch-local 0..15
  const int ej = (2 * tid) & 31;   // even unit index 0..30
  float cs0 = 0.f, cs1 = 0.f;

  u64t* gbase = hpub + (size_t)grp * 2 * (GB * 256);

  for (int t = 0; t < SS; ++t) {
    const u64t* hr = gbase + (size_t)((t & 1) ^ 1) * (GB * 256);
    u64t* hw = gbase + (size_t)(t & 1) * (GB * 256);
    const unsigned ewant = (unsigned)t;
    const unsigned epub = (unsigned)(t + 1);

    // ---- bulk-issue this thread's 16 h-atoms (coalesced: batch k, col tid)
    u64t q[16];
#pragma unroll
    for (int k = 0; k < 16; ++k) q[k] = ld_llc_u64(hr + k * 256 + tid);

    // ---- x @ W while atoms fly (cached loads; independent of q) ----
    float b0 = bia[c0i], b1 = bia[c1i];
    f32x4 acc0 = {b0, b0, b0, b0};
    f32x4 acc1 = {b1, b1, b1, b1};
    const __hip_bfloat16* xrow =
        xb + ((size_t)t * BB + grp * GB + l16) * II;
#pragma unroll
    for (int ks = 0; ks < II / 32; ++ks) {
      bf16x8 a = *(const bf16x8*)(xrow + ks * 32 + quad * 8);
      bf16x8 f0 = *(const bf16x8*)(wrow0 + ks * 32 + quad * 8);
      bf16x8 f1 = *(const bf16x8*)(wrow1 + ks * 32 + quad * 8);
      acc0 = __builtin_amdgcn_mfma_f32_16x16x32_bf16(a, f0, acc0, 0, 0, 0);
      acc1 = __builtin_amdgcn_mfma_f32_16x16x32_bf16(a, f1, acc1, 0, 0, 0);
    }

    // ---- ONE combined tag check; predicated re-poll of stale atoms only
    for (;;) {
      unsigned bad = 0;
#pragma unroll
      for (int k = 0; k < 16; ++k) bad |= ((unsigned)(q[k] >> 32) ^ ewant);
      if (bad == 0) break;
#pragma unroll
      for (int k = 0; k < 16; ++k)
        if ((unsigned)(q[k] >> 32) != ewant)
          q[k] = ld_llc_u64(hr + k * 256 + tid);
    }

    // ---- scatter h payloads to LDS: thread owns cols (2*tid,2*tid+1) of
    // every batch row ----
#pragma unroll
    for (int k = 0; k < 16; ++k)
      *(unsigned*)(&hL[k][2 * tid]) = (unsigned)q[k];
    __syncthreads();   // SYNC#1: hL complete

    // ---- h @ U from LDS ----
#pragma unroll 4
    for (int ks = 0; ks < HH / 32; ++ks) {
      bf16x8 a = *(const bf16x8*)(&hL[l16][ks * 32 + quad * 8]);
      bf16x8 f0 = *(const bf16x8*)(&Ut[c0i][ks * 32 + quad * 8]);
      bf16x8 f1 = *(const bf16x8*)(&Ut[c1i][ks * 32 + quad * 8]);
      acc0 = __builtin_amdgcn_mfma_f32_16x16x32_bf16(a, f0, acc0, 0, 0, 0);
      acc1 = __builtin_amdgcn_mfma_f32_16x16x32_bf16(a, f1, acc1, 0, 0, 0);
    }

    // D layout (verified m89): row = quad*4 + r (batch-local), col = lane's c
#pragma unroll
    for (int r = 0; r < 4; ++r) {
      gate[quad * 4 + r][c0i] = acc0[r];
      gate[quad * 4 + r][c1i] = acc1[r];
    }
    __syncthreads();   // SYNC#2: gates complete

    // ---- elementwise: 2 cells per thread ----
    float hv[2];
#pragma unroll
    for (int s = 0; s < 2; ++s) {
      int j = ej + s;
      float& cst = s ? cs1 : cs0;
      float xi = gate[eb][j];          // i-gate: local col 0*32+j
      float xf = gate[eb][32 + j];     // f
      float xg = gate[eb][64 + j];     // g
      float xo = gate[eb][96 + j];     // o
      float it = 1.f / (1.f + __expf(-xi));
      float ft = 1.f / (1.f + __expf(-xf));
      float gx = fminf(fmaxf(xg, -15.f), 15.f);
      float eg = __expf(2.f * gx);
      float gt = (eg - 1.f) / (eg + 1.f);
      float ot = 1.f / (1.f + __expf(-xo));
      cst = ft * cst + it * gt;
      float cc = fminf(fmaxf(cst, -15.f), 15.f);
      float ec = __expf(2.f * cc);
      float th = (ec - 1.f) / (ec + 1.f);
      hv[s] = ot * th;
    }

    // publish FIRST (critical path): tag<<32 | 2xbf16, one atom
    union { __hip_bfloat16 h2[2]; unsigned u; } hp;
    hp.h2[0] = __float2bfloat16(hv[0]);
    hp.h2[1] = __float2bfloat16(hv[1]);
    st_llc_u64(hw + eb * 256 + w16 * 16 + (ej >> 1),
               ((u64t)epub << 32) | (u64t)hp.u);

    // outputs
    int bglob = grp * GB + eb;
    int hglob = n0 + ej;
    *(float2*)(out + ((size_t)bglob * SS + t) * HH + hglob) =
        make_float2(hv[0], hv[1]);
    if (t == SS - 1) {
      size_t base = (size_t)BB * SS * HH;
      *(float2*)(out + base + (size_t)bglob * HH + hglob) =
          make_float2(hv[0], hv[1]);                        // h_f
      *(float2*)(out + base + (size_t)BB * HH + (size_t)bglob * HH + hglob) =
          make_float2(cs0, cs1);                            // c_f
    }
  }
}

extern "C" void kernel_launch(void* const* d_in, const int* in_sizes, int n_in,
                              void* d_out, int out_size, void* d_ws, size_t ws_size,
                              hipStream_t stream) {
  const float* x = (const float*)d_in[0];     // [64,512,256]
  const float* W = (const float*)d_in[1];     // [256,2048]
  const float* U = (const float*)d_in[2];     // [512,2048]
  const float* bias = (const float*)d_in[3];  // [2048]
  float* out = (float*)d_out;

  char* ws = (char*)d_ws;
  u64t* hpub = (u64t*)ws;                                   // 256 KB
  __hip_bfloat16* Wt = (__hip_bfloat16*)(ws + 256 * 1024);  // 1 MB
  __hip_bfloat16* xb = (__hip_bfloat16*)(ws + 256 * 1024 + G4 * II * 2);

  // zero hpub: tag 0 == epoch of h(-1), payload 0 == h(-1)=0
  hipMemsetAsync(d_ws, 0, 256 * 1024, stream);
  convert_x_kernel<<<BB * SS, II, 0, stream>>>(x, xb);
  transpose_w_kernel<<<128, 256, 0, stream>>>(W, Wt);
  lstm_step<<<NGRP * NWPG, 256, 0, stream>>>(U, bias, xb, Wt, hpub, out);
}